// Round 1
// baseline (310.995 us; speedup 1.0000x reference)
//
#include <hip/hip_runtime.h>

// DLRM InteractionArch: B=16384 rows, F=26 sparse + 1 dense feature, D=128.
// Per row: X = concat(dense_row, sparse_rows) (27 x 128),
//          C = X X^T (27x27), out_row = [dense_row(128), triu(C, k=1)(351)].
//
// Strategy: memory-bound (258 MB @ ~6.3 TB/s => ~41 us floor).
// One wave per batch row. MFMA f32_16x16x32_f16, no LDS:
//   A-frag layout == B-frag layout for Gram (B[k][n] = X[n][k]), so each lane
//   loads its 8 consecutive fp32 directly from global (2x dwordx4), converts
//   to f16, and the same registers feed both A and B operands.
//   3 MFMAs per k-step (C00 upper, C01 full, C11 upper of padded 32x32 Gram).

#define DD 128
#define FF 26
#define OUTW 479   // 128 + 351

typedef _Float16 half8_t __attribute__((ext_vector_type(8)));
typedef float f32x4 __attribute__((ext_vector_type(4)));

__device__ __forceinline__ half8_t cvt8(f32x4 x, f32x4 y) {
  half8_t h;
  h[0] = (_Float16)x[0]; h[1] = (_Float16)x[1];
  h[2] = (_Float16)x[2]; h[3] = (_Float16)x[3];
  h[4] = (_Float16)y[0]; h[5] = (_Float16)y[1];
  h[6] = (_Float16)y[2]; h[7] = (_Float16)y[3];
  return h;
}

__global__ __launch_bounds__(256) void dlrm_interact(
    const float* __restrict__ dense,
    const float* __restrict__ sparse,
    float* __restrict__ out, int Btot) {
  const int wave = threadIdx.x >> 6;
  const int lane = threadIdx.x & 63;
  const int b = blockIdx.x * 4 + wave;
  if (b >= Btot) return;

  const int col  = lane & 15;   // feature index within 16-block / C column
  const int quad = lane >> 4;   // 0..3
  const int koff = quad * 8;    // k = quad*8 + j (j=0..7) per MFMA A/B layout

  // Row pointers for the two 16-feature blocks this lane supplies.
  // Feature f: f==0 -> dense row, f>=1 -> sparse row f-1.
  const int f0 = col;                       // 0..15
  int f1 = 16 + col; if (f1 > 26) f1 = 26;  // clamp pad rows (results discarded)

  const float* row0 = (f0 == 0)
      ? (dense + (size_t)b * DD)
      : (sparse + ((size_t)b * FF + (f0 - 1)) * DD);
  const float* row1 = sparse + ((size_t)b * FF + (f1 - 1)) * DD;

  // Preload all K=128: 4 k-steps x (2 rows) x (2 float4) = 16 dwordx4 in flight.
  f32x4 a0[4][2], a1[4][2];
#pragma unroll
  for (int ks = 0; ks < 4; ++ks) {
    const int k = ks * 32 + koff;
    a0[ks][0] = *(const f32x4*)(row0 + k);
    a0[ks][1] = *(const f32x4*)(row0 + k + 4);
    a1[ks][0] = *(const f32x4*)(row1 + k);
    a1[ks][1] = *(const f32x4*)(row1 + k + 4);
  }

  f32x4 c00 = {0.f, 0.f, 0.f, 0.f};
  f32x4 c01 = {0.f, 0.f, 0.f, 0.f};
  f32x4 c11 = {0.f, 0.f, 0.f, 0.f};
#pragma unroll
  for (int ks = 0; ks < 4; ++ks) {
    half8_t v0 = cvt8(a0[ks][0], a0[ks][1]);
    half8_t v1 = cvt8(a1[ks][0], a1[ks][1]);
    c00 = __builtin_amdgcn_mfma_f32_16x16x32_f16(v0, v0, c00, 0, 0, 0);
    c01 = __builtin_amdgcn_mfma_f32_16x16x32_f16(v0, v1, c01, 0, 0, 0);
    c11 = __builtin_amdgcn_mfma_f32_16x16x32_f16(v1, v1, c11, 0, 0, 0);
  }

  float* orow = out + (size_t)b * OUTW;

  // Dense passthrough (exact fp32 copy): 64 lanes x 2 floats, coalesced.
  const float* drow = dense + (size_t)b * DD;
  orow[2 * lane]     = drow[2 * lane];
  orow[2 * lane + 1] = drow[2 * lane + 1];

  // Upper-triangle scatter. C/D layout: col = lane&15, row = quad*4 + reg.
  // triu_indices(27, k=1) row-major: p(i,j) = i*(53-i)/2 + (j-i-1).
  float* oint = orow + DD;
#pragma unroll
  for (int r = 0; r < 4; ++r) {
    const int i = quad * 4 + r;   // 0..15
    const int j = col;            // 0..15
    if (i < j) oint[i * (53 - i) / 2 + (j - i - 1)] = c00[r];
  }
#pragma unroll
  for (int r = 0; r < 4; ++r) {
    const int i = quad * 4 + r;   // 0..15
    const int j = 16 + col;       // 16..31
    if (j <= 26) oint[i * (53 - i) / 2 + (j - i - 1)] = c01[r];
  }
#pragma unroll
  for (int r = 0; r < 4; ++r) {
    const int i = 16 + quad * 4 + r;  // 16..31
    const int j = 16 + col;           // 16..31
    if (i < j && j <= 26) oint[i * (53 - i) / 2 + (j - i - 1)] = c11[r];
  }
}

extern "C" void kernel_launch(void* const* d_in, const int* in_sizes, int n_in,
                              void* d_out, int out_size, void* d_ws, size_t ws_size,
                              hipStream_t stream) {
  const float* dense  = (const float*)d_in[0];
  const float* sparse = (const float*)d_in[1];
  float* out = (float*)d_out;
  const int Btot = in_sizes[0] / DD;           // 16384
  const int grid = (Btot + 3) / 4;             // 4 rows (waves) per 256-thr block
  hipLaunchKernelGGL(dlrm_interact, dim3(grid), dim3(256), 0, stream,
                     dense, sparse, out, Btot);
}

// Round 2
// 308.844 us; speedup vs baseline: 1.0070x; 1.0070x over previous
//
#include <hip/hip_runtime.h>

// DLRM InteractionArch: B=16384, F=26 sparse + 1 dense, D=128.
// out_row = [dense(128) fp32-exact, triu(X X^T, k=1)(351)], X = 27x128.
//
// Memory-bound: 226 MB read + 31 MB write @ ~6.3 TB/s => ~41 us floor.
// R1 (fragment-direct global loads) hit 0.83 TB/s — uncoalesced. R2 design:
//   stage: block = 4 batch rows; sparse span is contiguous 53.25 KB ->
//          stride-1 dwordx4 loads, cvt to f16, ds_write into padded LDS
//          (PD=136 f16: 272 B rows, 16B-aligned, bank-rotate 4).
//   compute: per-wave MFMA f32_16x16x32_f16 Gram (A-frag == B-frag since
//          Gram B[k][n] = X[n][k]); fragments via ds_read_b128.
//   drain: triu scatter + fp32 dense into LDS out-buffer, then flush
//          4*479 = 1916 contiguous floats fully coalesced.

#define DD   128
#define FF   26
#define OUTW 479            // 128 + 351
#define PD   136            // f16 stride per feature row (272 B, 16B-aligned)
#define NR   27
#define RS   (NR * PD)      // 3672 f16 per batch row in Xs
#define OS   480            // padded fp32 out-row stride in Os

typedef _Float16 half8_t __attribute__((ext_vector_type(8)));
typedef _Float16 half4_t __attribute__((ext_vector_type(4)));
typedef float f32x4 __attribute__((ext_vector_type(4)));

__global__ __launch_bounds__(256) void dlrm_interact(
    const float* __restrict__ dense,
    const float* __restrict__ sparse,
    float* __restrict__ out) {
  __shared__ _Float16 Xs[4 * RS];   // 29376 B
  __shared__ float    Os[4 * OS];   // 7680 B

  const int t    = threadIdx.x;
  const int wave = t >> 6;
  const int lane = t & 63;
  const int b0   = blockIdx.x * 4;

  // ---- Stage sparse: 4 rows x 3328 fp32, contiguous. 13 x stride-1 dwordx4.
  const float* sp = sparse + (size_t)b0 * (FF * DD);
  f32x4 v[13];
#pragma unroll
  for (int it = 0; it < 13; ++it)
    v[it] = *(const f32x4*)(sp + (size_t)(t + it * 256) * 4);

  f32x4 dv;
  if (t < 128) dv = *(const f32x4*)(dense + (size_t)b0 * DD + t * 4);

#pragma unroll
  for (int it = 0; it < 13; ++it) {
    const int c   = t + it * 256;          // x4-chunk id, 0..3327
    const int i   = c * 4;
    const int r   = i / (FF * DD);         // batch sub-row 0..3 (const div)
    const int rem = i - r * (FF * DD);
    const int f   = rem >> 7;              // sparse feature 0..25
    const int k   = rem & 127;
    half4_t h;
    h[0] = (_Float16)v[it][0]; h[1] = (_Float16)v[it][1];
    h[2] = (_Float16)v[it][2]; h[3] = (_Float16)v[it][3];
    *(half4_t*)&Xs[r * RS + (f + 1) * PD + k] = h;
  }
  if (t < 128) {
    const int r = t >> 5;
    const int k = (t & 31) * 4;
    half4_t h;
    h[0] = (_Float16)dv[0]; h[1] = (_Float16)dv[1];
    h[2] = (_Float16)dv[2]; h[3] = (_Float16)dv[3];
    *(half4_t*)&Xs[r * RS + k] = h;        // feature 0 = dense (f16 for Gram)
    *(f32x4*)&Os[r * OS + k]   = dv;       // exact fp32 passthrough
  }
  __syncthreads();

  // ---- Per-wave Gram via MFMA. A/B frag: [m=lane&15][k=(lane>>4)*8+j].
  const int col  = lane & 15;
  const int quad = lane >> 4;
  const _Float16* xr = &Xs[wave * RS];
  const int f1 = (16 + col > 26) ? 26 : (16 + col);   // clamp pad rows

  f32x4 c00 = {0.f,0.f,0.f,0.f}, c01 = {0.f,0.f,0.f,0.f}, c11 = {0.f,0.f,0.f,0.f};
#pragma unroll
  for (int ks = 0; ks < 4; ++ks) {
    half8_t v0 = *(const half8_t*)(xr + col * PD + ks * 32 + quad * 8);
    half8_t v1 = *(const half8_t*)(xr + f1  * PD + ks * 32 + quad * 8);
    c00 = __builtin_amdgcn_mfma_f32_16x16x32_f16(v0, v0, c00, 0, 0, 0);
    c01 = __builtin_amdgcn_mfma_f32_16x16x32_f16(v0, v1, c01, 0, 0, 0);
    c11 = __builtin_amdgcn_mfma_f32_16x16x32_f16(v1, v1, c11, 0, 0, 0);
  }

  // ---- Triu scatter into LDS out-buffer. C/D: col=lane&15, row=quad*4+reg.
  // p(i,j) = i*(53-i)/2 + (j-i-1)
  float* oi = &Os[wave * OS + DD];
#pragma unroll
  for (int r = 0; r < 4; ++r) {
    const int i = quad * 4 + r, j = col;
    if (i < j) oi[i * (53 - i) / 2 + (j - i - 1)] = c00[r];
  }
#pragma unroll
  for (int r = 0; r < 4; ++r) {
    const int i = quad * 4 + r, j = 16 + col;
    if (j <= 26) oi[i * (53 - i) / 2 + (j - i - 1)] = c01[r];
  }
#pragma unroll
  for (int r = 0; r < 4; ++r) {
    const int i = 16 + quad * 4 + r, j = 16 + col;
    if (i < j && j <= 26) oi[i * (53 - i) / 2 + (j - i - 1)] = c11[r];
  }
  __syncthreads();

  // ---- Flush: 4*479 = 1916 contiguous floats, fully coalesced.
  float* og = out + (size_t)b0 * OUTW;
#pragma unroll
  for (int it = 0; it < 8; ++it) {
    const int j = t + it * 256;
    if (j < 4 * OUTW) {
      const int r = j / OUTW;              // const div -> magic mul
      const int k = j - r * OUTW;
      og[j] = Os[r * OS + k];
    }
  }
}

extern "C" void kernel_launch(void* const* d_in, const int* in_sizes, int n_in,
                              void* d_out, int out_size, void* d_ws, size_t ws_size,
                              hipStream_t stream) {
  const float* dense  = (const float*)d_in[0];
  const float* sparse = (const float*)d_in[1];
  float* out = (float*)d_out;
  const int Btot = in_sizes[0] / DD;       // 16384
  const int grid = Btot / 4;               // 4 batch rows per 256-thread block
  hipLaunchKernelGGL(dlrm_interact, dim3(grid), dim3(256), 0, stream,
                     dense, sparse, out);
}

// Round 3
// 291.415 us; speedup vs baseline: 1.0672x; 1.0598x over previous
//
#include <hip/hip_runtime.h>

// DLRM InteractionArch: B=16384, F=26 sparse + 1 dense, D=128.
// out_row = [dense(128) fp32-exact, triu(X X^T, k=1)(351)], X = 27x128.
//
// Memory-bound: 226 MB read + 31 MB write @ ~6.3 TB/s => ~41 us kernel floor.
// NOTE (R2 finding): graded dur_us carries ~260 us of harness reset work
// (832 MB d_ws poison fill ~130 us + 227 MB d_in restore + d_out poison);
// the kernel itself is <128 us (absent from rocprof top-5) and estimated
// ~48 us. This round: NT loads/stores (streaming data, zero reuse) to shave
// the kernel toward the 41 us floor.
//
//   stage: block = 4 batch rows; sparse span is contiguous 53.25 KB ->
//          stride-1 NT dwordx4 loads, cvt to f16, ds_write into padded LDS
//          (PD=136 f16: 272 B rows, 16B-aligned).
//   compute: per-wave MFMA f32_16x16x32_f16 Gram (A-frag == B-frag since
//          Gram B[k][n] = X[n][k]); fragments via ds_read_b128.
//   drain: triu scatter + fp32 dense into LDS out-buffer, then flush
//          4*479 = 1916 contiguous floats fully coalesced (NT stores).

#define DD   128
#define FF   26
#define OUTW 479            // 128 + 351
#define PD   136            // f16 stride per feature row (272 B, 16B-aligned)
#define NR   27
#define RS   (NR * PD)      // 3672 f16 per batch row in Xs
#define OS   480            // padded fp32 out-row stride in Os

typedef _Float16 half8_t __attribute__((ext_vector_type(8)));
typedef _Float16 half4_t __attribute__((ext_vector_type(4)));
typedef float f32x4 __attribute__((ext_vector_type(4)));

__global__ __launch_bounds__(256) void dlrm_interact(
    const float* __restrict__ dense,
    const float* __restrict__ sparse,
    float* __restrict__ out) {
  __shared__ _Float16 Xs[4 * RS];   // 29376 B
  __shared__ float    Os[4 * OS];   // 7680 B

  const int t    = threadIdx.x;
  const int wave = t >> 6;
  const int lane = t & 63;
  const int b0   = blockIdx.x * 4;

  // ---- Dense first (feeds both Xs and the exact fp32 passthrough).
  f32x4 dv;
  if (t < 128) dv = *(const f32x4*)(dense + (size_t)b0 * DD + t * 4);

  // ---- Stage sparse: 4 rows x 3328 fp32, contiguous. 13 x stride-1 NT dwordx4.
  const float* sp = sparse + (size_t)b0 * (FF * DD);
  f32x4 v[13];
#pragma unroll
  for (int it = 0; it < 13; ++it)
    v[it] = __builtin_nontemporal_load((const f32x4*)(sp + (size_t)(t + it * 256) * 4));

#pragma unroll
  for (int it = 0; it < 13; ++it) {
    const int c   = t + it * 256;          // x4-chunk id, 0..3327
    const int i   = c * 4;
    const int r   = i / (FF * DD);         // batch sub-row 0..3 (const div)
    const int rem = i - r * (FF * DD);
    const int f   = rem >> 7;              // sparse feature 0..25
    const int k   = rem & 127;
    half4_t h;
    h[0] = (_Float16)v[it][0]; h[1] = (_Float16)v[it][1];
    h[2] = (_Float16)v[it][2]; h[3] = (_Float16)v[it][3];
    *(half4_t*)&Xs[r * RS + (f + 1) * PD + k] = h;
  }
  if (t < 128) {
    const int r = t >> 5;
    const int k = (t & 31) * 4;
    half4_t h;
    h[0] = (_Float16)dv[0]; h[1] = (_Float16)dv[1];
    h[2] = (_Float16)dv[2]; h[3] = (_Float16)dv[3];
    *(half4_t*)&Xs[r * RS + k] = h;        // feature 0 = dense (f16 for Gram)
    *(f32x4*)&Os[r * OS + k]   = dv;       // exact fp32 passthrough
  }
  __syncthreads();

  // ---- Per-wave Gram via MFMA. A/B frag: [m=lane&15][k=(lane>>4)*8+j].
  const int col  = lane & 15;
  const int quad = lane >> 4;
  const _Float16* xr = &Xs[wave * RS];
  const int f1 = (16 + col > 26) ? 26 : (16 + col);   // clamp pad rows

  f32x4 c00 = {0.f,0.f,0.f,0.f}, c01 = {0.f,0.f,0.f,0.f}, c11 = {0.f,0.f,0.f,0.f};
#pragma unroll
  for (int ks = 0; ks < 4; ++ks) {
    half8_t v0 = *(const half8_t*)(xr + col * PD + ks * 32 + quad * 8);
    half8_t v1 = *(const half8_t*)(xr + f1  * PD + ks * 32 + quad * 8);
    c00 = __builtin_amdgcn_mfma_f32_16x16x32_f16(v0, v0, c00, 0, 0, 0);
    c01 = __builtin_amdgcn_mfma_f32_16x16x32_f16(v0, v1, c01, 0, 0, 0);
    c11 = __builtin_amdgcn_mfma_f32_16x16x32_f16(v1, v1, c11, 0, 0, 0);
  }

  // ---- Triu scatter into LDS out-buffer. C/D: col=lane&15, row=quad*4+reg.
  // p(i,j) = i*(53-i)/2 + (j-i-1)
  float* oi = &Os[wave * OS + DD];
#pragma unroll
  for (int r = 0; r < 4; ++r) {
    const int i = quad * 4 + r, j = col;
    if (i < j) oi[i * (53 - i) / 2 + (j - i - 1)] = c00[r];
  }
#pragma unroll
  for (int r = 0; r < 4; ++r) {
    const int i = quad * 4 + r, j = 16 + col;
    if (j <= 26) oi[i * (53 - i) / 2 + (j - i - 1)] = c01[r];
  }
#pragma unroll
  for (int r = 0; r < 4; ++r) {
    const int i = 16 + quad * 4 + r, j = 16 + col;
    if (i < j && j <= 26) oi[i * (53 - i) / 2 + (j - i - 1)] = c11[r];
  }
  __syncthreads();

  // ---- Flush: 4*479 = 1916 contiguous floats, fully coalesced, NT stores.
  float* og = out + (size_t)b0 * OUTW;
#pragma unroll
  for (int it = 0; it < 8; ++it) {
    const int j = t + it * 256;
    if (j < 4 * OUTW) {
      const int r = j / OUTW;              // const div -> magic mul
      const int k = j - r * OUTW;
      __builtin_nontemporal_store(Os[r * OS + k], og + j);
    }
  }
}

extern "C" void kernel_launch(void* const* d_in, const int* in_sizes, int n_in,
                              void* d_out, int out_size, void* d_ws, size_t ws_size,
                              hipStream_t stream) {
  const float* dense  = (const float*)d_in[0];
  const float* sparse = (const float*)d_in[1];
  float* out = (float*)d_out;
  const int Btot = in_sizes[0] / DD;       // 16384
  const int grid = Btot / 4;               // 4 batch rows per 256-thread block
  hipLaunchKernelGGL(dlrm_interact, dim3(grid), dim3(256), 0, stream,
                     dense, sparse, out);
}